// Round 7
// baseline (214.536 us; speedup 1.0000x reference)
//
#include <hip/hip_runtime.h>

// out[b] = 0.75 * sum_i x[b,i] * s[i],  s[i] = sum_h W[h,i]
// x: [2048, 8192] f32 ; W: [8192, 8192] f32 ; out: [2048] f32
//
// ATTRIBUTION ROUND: R1-exact structure, but colsum dispatched 4x.
// s accumulates 4*colsum; rowdot scales by 0.75/4. Marginal cost of the
// 3 extra (LLC-warm) colsum dispatches = (dur - 78.5)/3.

#define I_SIZE 8192
#define H_SIZE 8192
#define BATCH  2048
#define ROWS_PER_CHUNK 64

// ---- Kernel 1: panel colsum (R1 EXACT) ------------------------------------
__global__ __launch_bounds__(256) void colsum_kernel(const float* __restrict__ W,
                                                     float* __restrict__ s) {
    const int col = blockIdx.x * 1024 + threadIdx.x * 4;
    const size_t r0 = (size_t)blockIdx.y * ROWS_PER_CHUNK;
    const float* base = W + r0 * I_SIZE + col;

    float4 acc = make_float4(0.f, 0.f, 0.f, 0.f);
#pragma unroll 8
    for (int r = 0; r < ROWS_PER_CHUNK; ++r) {
        float4 v = *reinterpret_cast<const float4*>(base + (size_t)r * I_SIZE);
        acc.x += v.x; acc.y += v.y; acc.z += v.z; acc.w += v.w;
    }
    atomicAdd(&s[col + 0], acc.x);
    atomicAdd(&s[col + 1], acc.y);
    atomicAdd(&s[col + 2], acc.z);
    atomicAdd(&s[col + 3], acc.w);
}

// ---- Kernel 2: rowdot (R1 EXACT except scale 0.75/4) ----------------------
__global__ __launch_bounds__(256) void rowdot_kernel(const float* __restrict__ x,
                                                     const float* __restrict__ s,
                                                     float* __restrict__ out) {
    const int b = blockIdx.x;
    const float* xr = x + (size_t)b * I_SIZE;

    float acc = 0.f;
#pragma unroll
    for (int i = threadIdx.x * 4; i < I_SIZE; i += 256 * 4) {
        float4 xv = *reinterpret_cast<const float4*>(xr + i);
        float4 sv = *reinterpret_cast<const float4*>(s + i);
        acc += xv.x * sv.x + xv.y * sv.y + xv.z * sv.z + xv.w * sv.w;
    }

#pragma unroll
    for (int off = 32; off; off >>= 1)
        acc += __shfl_down(acc, off, 64);

    __shared__ float partial[4];
    const int lane = threadIdx.x & 63;
    const int wid  = threadIdx.x >> 6;
    if (lane == 0) partial[wid] = acc;
    __syncthreads();
    if (threadIdx.x == 0)
        out[b] = 0.1875f * (partial[0] + partial[1] + partial[2] + partial[3]);
}

extern "C" void kernel_launch(void* const* d_in, const int* in_sizes, int n_in,
                              void* d_out, int out_size, void* d_ws, size_t ws_size,
                              hipStream_t stream) {
    const float* x = (const float*)d_in[0];   // [BATCH, I_SIZE]
    const float* W = (const float*)d_in[1];   // [H_SIZE, I_SIZE]
    float* out = (float*)d_out;               // [BATCH]
    float* s   = (float*)d_ws;                // [I_SIZE]

    hipMemsetAsync(s, 0, I_SIZE * sizeof(float), stream);

    dim3 grid1(I_SIZE / 1024, H_SIZE / ROWS_PER_CHUNK);
    colsum_kernel<<<grid1, 256, 0, stream>>>(W, s);   // #1 (cold-ish)
    colsum_kernel<<<grid1, 256, 0, stream>>>(W, s);   // #2 (LLC-warm)
    colsum_kernel<<<grid1, 256, 0, stream>>>(W, s);   // #3 (LLC-warm)
    colsum_kernel<<<grid1, 256, 0, stream>>>(W, s);   // #4 (LLC-warm)

    rowdot_kernel<<<BATCH, 256, 0, stream>>>(x, s, out);
}

// Round 8
// 213.147 us; speedup vs baseline: 1.0065x; 1.0065x over previous
//
#include <hip/hip_runtime.h>

// out[b] = 0.75 * sum_i x[b,i] * s[i],  s[i] = sum_h W[h,i]
// x: [2048, 8192] f32 ; W: [8192, 8192] f32 ; out: [2048] f32
//
// 2 dispatches: memset(s+counter) ; ONE fused kernel.
// Barrier redesigned after R5 post-mortem: RELAXED spin loads (no per-iter
// buffer_inv), RELEASE add on entry, single ACQUIRE at exit. x rows are
// prefetched into registers BEFORE the barrier so the 64 MB x-read hides
// under colsum tail/skew. 1024 blocks x 4/CU (launch_bounds-enforced) =
// all resident -> no deadlock; spin bounded as a hang-safety valve.

#define I_SIZE 8192
#define H_SIZE 8192
#define BATCH  2048
#define NB     1024

__global__ __launch_bounds__(256, 4) void fused_kernel(
    const float* __restrict__ x, const float* __restrict__ W,
    float* __restrict__ s, unsigned* __restrict__ counter,
    float* __restrict__ out) {
  const int t = threadIdx.x;
  const int bid = blockIdx.x;

  // ---- Phase A: panel colsum (R1-exact pattern) ---------------------------
  {
    const int col = (bid & 7) * 1024 + t * 4;
    const size_t r0 = (size_t)(bid >> 3) * 64;
    const float* base = W + r0 * I_SIZE + col;
    float4 acc = make_float4(0.f, 0.f, 0.f, 0.f);
#pragma unroll 8
    for (int r = 0; r < 64; ++r) {
      float4 v = *reinterpret_cast<const float4*>(base + (size_t)r * I_SIZE);
      acc.x += v.x; acc.y += v.y; acc.z += v.z; acc.w += v.w;
    }
    atomicAdd(&s[col + 0], acc.x);   // device-scope: RMW at coherent point
    atomicAdd(&s[col + 1], acc.y);
    atomicAdd(&s[col + 2], acc.z);
    atomicAdd(&s[col + 3], acc.w);
  }

  // ---- Prefetch x rows 2*bid, 2*bid+1 into registers (independent of s) ---
  const float* x0 = x + (size_t)(2 * bid) * I_SIZE;
  const float* x1 = x0 + I_SIZE;
  float4 xa[8], xb[8];
#pragma unroll
  for (int j = 0; j < 8; ++j) {
    const int i = t * 4 + j * 1024;
    xa[j] = *reinterpret_cast<const float4*>(x0 + i);
    xb[j] = *reinterpret_cast<const float4*>(x1 + i);
  }

  // ---- Grid barrier: release add, RELAXED spin, one acquire ---------------
  __syncthreads();   // drains vmcnt: s-atomics issued+complete, x in regs
  if (t == 0) {
    __hip_atomic_fetch_add(counter, 1u, __ATOMIC_RELEASE,
                           __HIP_MEMORY_SCOPE_AGENT);
    int guard = 0;
    while (__hip_atomic_load(counter, __ATOMIC_RELAXED,
                             __HIP_MEMORY_SCOPE_AGENT) < NB &&
           guard < 1000000) {
      __builtin_amdgcn_s_sleep(32);   // ~2k clocks; no cache ops while waiting
      ++guard;
    }
  }
  __syncthreads();
  // one-time acquire: invalidate stale L1/L2 copies before plain s-loads
  unsigned chk = __hip_atomic_load(counter, __ATOMIC_ACQUIRE,
                                   __HIP_MEMORY_SCOPE_AGENT);
  asm volatile("" :: "v"(chk));      // keep the acquire load alive

  // ---- Phase B: dot both prefetched rows with s ---------------------------
  float a0 = 0.f, a1 = 0.f;
#pragma unroll
  for (int j = 0; j < 8; ++j) {
    const int i = t * 4 + j * 1024;
    const float4 sv = *reinterpret_cast<const float4*>(s + i);
    a0 += xa[j].x * sv.x + xa[j].y * sv.y + xa[j].z * sv.z + xa[j].w * sv.w;
    a1 += xb[j].x * sv.x + xb[j].y * sv.y + xb[j].z * sv.z + xb[j].w * sv.w;
  }
#pragma unroll
  for (int off = 32; off; off >>= 1) {
    a0 += __shfl_down(a0, off, 64);
    a1 += __shfl_down(a1, off, 64);
  }
  __shared__ float p0[4], p1[4];
  const int lane = t & 63, wid = t >> 6;
  if (lane == 0) { p0[wid] = a0; p1[wid] = a1; }
  __syncthreads();
  if (t == 0) out[2 * bid]     = 0.75f * (p0[0] + p0[1] + p0[2] + p0[3]);
  if (t == 1) out[2 * bid + 1] = 0.75f * (p1[0] + p1[1] + p1[2] + p1[3]);
}

extern "C" void kernel_launch(void* const* d_in, const int* in_sizes, int n_in,
                              void* d_out, int out_size, void* d_ws, size_t ws_size,
                              hipStream_t stream) {
  const float* x = (const float*)d_in[0];   // [BATCH, I_SIZE]
  const float* W = (const float*)d_in[1];   // [H_SIZE, I_SIZE]
  float* out = (float*)d_out;               // [BATCH]

  float*    s       = (float*)d_ws;                      // 32 KiB
  unsigned* counter = (unsigned*)((char*)d_ws + 32768);  // 4 B

  hipMemsetAsync(d_ws, 0, 32768 + sizeof(unsigned), stream);
  fused_kernel<<<NB, 256, 0, stream>>>(x, W, s, counter, out);
}

// Round 9
// 77.007 us; speedup vs baseline: 2.7859x; 2.7679x over previous
//
#include <hip/hip_runtime.h>

// out[b] = 0.75 * sum_i x[b,i] * s[i],  s[i] = sum_h W[h,i]
// x: [2048, 8192] f32 ; W: [8192, 8192] f32 ; out: [2048] f32
//
// R1 structure (memset ; colsum ; rowdot). Single change vs R1:
// rowdot processes 2 rows/block (1024 blocks) so each s float4 load is
// reused for two rows -> s re-read request traffic halved (64->32 MB).

#define I_SIZE 8192
#define H_SIZE 8192
#define BATCH  2048
#define ROWS_PER_CHUNK 64

// ---- Kernel 1: panel colsum (R1 EXACT; 45-47 us, 90% of float4 ceiling) ---
__global__ __launch_bounds__(256) void colsum_kernel(const float* __restrict__ W,
                                                     float* __restrict__ s) {
    const int col = blockIdx.x * 1024 + threadIdx.x * 4;
    const size_t r0 = (size_t)blockIdx.y * ROWS_PER_CHUNK;
    const float* base = W + r0 * I_SIZE + col;

    float4 acc = make_float4(0.f, 0.f, 0.f, 0.f);
#pragma unroll 8
    for (int r = 0; r < ROWS_PER_CHUNK; ++r) {
        float4 v = *reinterpret_cast<const float4*>(base + (size_t)r * I_SIZE);
        acc.x += v.x; acc.y += v.y; acc.z += v.z; acc.w += v.w;
    }
    atomicAdd(&s[col + 0], acc.x);
    atomicAdd(&s[col + 1], acc.y);
    atomicAdd(&s[col + 2], acc.z);
    atomicAdd(&s[col + 3], acc.w);
}

// ---- Kernel 2: rowdot, 2 rows/block (1024 blocks, 4/CU) -------------------
__global__ __launch_bounds__(256) void rowdot2_kernel(const float* __restrict__ x,
                                                      const float* __restrict__ s,
                                                      float* __restrict__ out) {
    const int t = threadIdx.x;
    const int b = blockIdx.x;
    const float* x0 = x + (size_t)(2 * b) * I_SIZE;
    const float* x1 = x0 + I_SIZE;

    float a0 = 0.f, a1 = 0.f;
#pragma unroll
    for (int j = 0; j < 8; ++j) {
        const int i = t * 4 + j * 1024;
        const float4 sv = *reinterpret_cast<const float4*>(s + i);
        const float4 v0 = *reinterpret_cast<const float4*>(x0 + i);
        const float4 v1 = *reinterpret_cast<const float4*>(x1 + i);
        a0 += v0.x * sv.x + v0.y * sv.y + v0.z * sv.z + v0.w * sv.w;
        a1 += v1.x * sv.x + v1.y * sv.y + v1.z * sv.z + v1.w * sv.w;
    }

#pragma unroll
    for (int off = 32; off; off >>= 1) {
        a0 += __shfl_down(a0, off, 64);
        a1 += __shfl_down(a1, off, 64);
    }

    __shared__ float p0[4], p1[4];
    const int lane = t & 63, wid = t >> 6;
    if (lane == 0) { p0[wid] = a0; p1[wid] = a1; }
    __syncthreads();
    if (t == 0) out[2 * b]     = 0.75f * (p0[0] + p0[1] + p0[2] + p0[3]);
    if (t == 1) out[2 * b + 1] = 0.75f * (p1[0] + p1[1] + p1[2] + p1[3]);
}

extern "C" void kernel_launch(void* const* d_in, const int* in_sizes, int n_in,
                              void* d_out, int out_size, void* d_ws, size_t ws_size,
                              hipStream_t stream) {
    const float* x = (const float*)d_in[0];   // [BATCH, I_SIZE]
    const float* W = (const float*)d_in[1];   // [H_SIZE, I_SIZE]
    float* out = (float*)d_out;               // [BATCH]
    float* s   = (float*)d_ws;                // [I_SIZE]

    hipMemsetAsync(s, 0, I_SIZE * sizeof(float), stream);

    dim3 grid1(I_SIZE / 1024, H_SIZE / ROWS_PER_CHUNK);
    colsum_kernel<<<grid1, 256, 0, stream>>>(W, s);
    rowdot2_kernel<<<BATCH / 2, 256, 0, stream>>>(x, s, out);
}